// Round 12
// baseline (341.991 us; speedup 1.0000x reference)
//
#include <hip/hip_runtime.h>

#define NN 200000
#define NE 1000000
#define DD 64
#define NCHUNK 196   // ceil(NN / 1024)

typedef __bf16 bf16x4 __attribute__((ext_vector_type(4)));
typedef __bf16 bf16x8 __attribute__((ext_vector_type(8)));
typedef float  f32x4  __attribute__((ext_vector_type(4)));

static __device__ __forceinline__ bf16x8 pack8(const float* __restrict__ p) {
    float4 a = *reinterpret_cast<const float4*>(p);
    float4 b = *reinterpret_cast<const float4*>(p + 4);
    bf16x8 r;
    r[0] = (__bf16)a.x; r[1] = (__bf16)a.y; r[2] = (__bf16)a.z; r[3] = (__bf16)a.w;
    r[4] = (__bf16)b.x; r[5] = (__bf16)b.y; r[6] = (__bf16)b.z; r[7] = (__bf16)b.w;
    return r;
}

// ---------- counts zero ----------
__global__ __launch_bounds__(256) void k_zero(int* __restrict__ counts) {
    const int i = (blockIdx.x * 256 + threadIdx.x) * 4;
    if (i + 3 < NN) *reinterpret_cast<int4*>(counts + i) = make_int4(0, 0, 0, 0);
    else for (int j = i; j < NN; ++j) counts[j] = 0;
}

// ---------- histogram ----------
__global__ __launch_bounds__(256) void k_hist(const int* __restrict__ dst,
                                              int* __restrict__ counts) {
    for (int e = blockIdx.x * blockDim.x + threadIdx.x; e < NE;
         e += gridDim.x * blockDim.x)
        atomicAdd(&counts[dst[e]], 1);
}

// ---------- CSR scan ----------
__global__ __launch_bounds__(256) void k_chunk_sums(const int* __restrict__ counts,
                                                    int* __restrict__ csum) {
    const int b = blockIdx.x, tid = threadIdx.x;
    const int base = b * 1024 + tid * 4;
    int s = 0;
#pragma unroll
    for (int j = 0; j < 4; ++j) {
        const int i = base + j;
        if (i < NN) s += counts[i];
    }
#pragma unroll
    for (int d = 32; d > 0; d >>= 1) s += __shfl_down(s, d);
    __shared__ int wsum[4];
    if ((tid & 63) == 0) wsum[tid >> 6] = s;
    __syncthreads();
    if (tid == 0) csum[b] = wsum[0] + wsum[1] + wsum[2] + wsum[3];
}

__global__ void k_scan_chunks(const int* __restrict__ csum, int* __restrict__ cofs) {
    if (threadIdx.x == 0 && blockIdx.x == 0) {
        int acc = 0;
        for (int i = 0; i < NCHUNK; ++i) { cofs[i] = acc; acc += csum[i]; }
    }
}

__global__ __launch_bounds__(256) void k_chunk_scan(const int* __restrict__ counts,
                                                    const int* __restrict__ cofs,
                                                    int* __restrict__ offs,
                                                    int* __restrict__ cursor) {
    const int b = blockIdx.x, tid = threadIdx.x;
    const int lane = tid & 63, wv = tid >> 6;
    const int base = b * 1024 + tid * 4;
    if (b == 0 && tid == 0) offs[NN] = NE;   // sentinel
    int c[4];
#pragma unroll
    for (int j = 0; j < 4; ++j) {
        const int i = base + j;
        c[j] = (i < NN) ? counts[i] : 0;
    }
    const int ls = c[0] + c[1] + c[2] + c[3];
    int v = ls;
#pragma unroll
    for (int d = 1; d < 64; d <<= 1) {
        const int u = __shfl_up(v, d);
        if (lane >= d) v += u;
    }
    __shared__ int wsum[4];
    if (lane == 63) wsum[wv] = v;
    __syncthreads();
    int wbase = 0;
    for (int w = 0; w < wv; ++w) wbase += wsum[w];
    int excl = cofs[b] + wbase + (v - ls);
#pragma unroll
    for (int j = 0; j < 4; ++j) {
        const int i = base + j;
        if (i < NN) { offs[i] = excl; cursor[i] = excl; }
        excl += c[j];
    }
}

// ---------- Fused permfill (blocks 0..1023) || ftc conversion (rest) ----------
// ftc[s][j*8+0..3] = bf16(f2[s][j*4..]*ci[s]); ftc[s][j*8+4..7] = bf16(f3[..]*ci[s])
__global__ __launch_bounds__(256) void k_fill_conv(
    const int* __restrict__ dst, const int* __restrict__ src,
    const float* __restrict__ ci, const float* __restrict__ f2,
    const float* __restrict__ f3, int* __restrict__ cursor,
    int4* __restrict__ epack, __bf16* __restrict__ ftc)
{
    const int b = blockIdx.x;
    if (b < 1024) {
        for (int e = b * 256 + threadIdx.x; e < NE; e += 1024 * 256) {
            const int s = src[e];
            const float cs = ci[s];
            const int pos = atomicAdd(&cursor[dst[e]], 1);
            epack[pos] = make_int4(e, s, __float_as_int(cs), 0);
        }
    } else {
        const int nconv = (gridDim.x - 1024) * 256;
        const int total = NN * 16;                    // 16B output chunks
        for (int cch = (b - 1024) * 256 + threadIdx.x; cch < total; cch += nconv) {
            const int row = cch >> 4;
            const int t   = cch & 15;
            const float c = ci[row];
            const float4 a = *reinterpret_cast<const float4*>(f2 + (size_t)row * DD + t * 4);
            const float4 v = *reinterpret_cast<const float4*>(f3 + (size_t)row * DD + t * 4);
            bf16x8 o;
            o[0] = (__bf16)(a.x * c); o[1] = (__bf16)(a.y * c);
            o[2] = (__bf16)(a.z * c); o[3] = (__bf16)(a.w * c);
            o[4] = (__bf16)(v.x * c); o[5] = (__bf16)(v.y * c);
            o[6] = (__bf16)(v.z * c); o[7] = (__bf16)(v.w * c);
            *reinterpret_cast<bf16x8*>(ftc + (size_t)row * 128 + t * 8) = o;
        }
    }
}

// ---------- Work-balanced pull + per-wave MFMA epilogue (no block barrier) ----------
// Wave owns 16 nodes; quarter q walks nodes n0q..n0q+3 as ONE flattened CSR
// range with boundary finalization -> wave time ~ max of 4 Gamma(20), 81% eff.
__global__ __launch_bounds__(256) void k_pull_ws(
    const int4* __restrict__ epack, const int* __restrict__ offs,
    const float* __restrict__ review, const float* __restrict__ ci,
    const __bf16* __restrict__ ftc,
    const float* __restrict__ W1, const float* __restrict__ W2,
    float* __restrict__ out_rst, float* __restrict__ out_re,
    float* __restrict__ out_id)
{
    __shared__ __bf16 At[4][16][72];   // per-wave bf16(cid*hx) tile (padded)
    __shared__ float  S2[4][16][68];   // per-wave cid*sum(f2c) tile (padded)

    const int tid   = threadIdx.x;
    const int w     = tid >> 6;
    const int lane  = tid & 63;
    const int l16   = lane & 15;
    const int q     = lane >> 4;
    const int wbase = blockIdx.x * 64 + w * 16;   // wave's 16 nodes
    const int n0q   = wbase + q * 4;              // quarter's 4 nodes

    int pos = offs[n0q];
    const int posEnd = offs[n0q + 4];
    int j   = 0;
    int bnd = offs[n0q + 1];

    float4 ax = make_float4(0.f, 0.f, 0.f, 0.f);
    float4 a2 = make_float4(0.f, 0.f, 0.f, 0.f);
    float4 a3 = make_float4(0.f, 0.f, 0.f, 0.f);

    int4 ep = epack[pos < posEnd ? pos : (NE - 1)];   // 1-ahead pipeline seed

    for (;;) {
        // finalize completed nodes (handles cnt==0 runs)
        while (j < 4 && pos == bnd) {
            const int n = n0q + j;
            const float cid = ci[n];
            f32x4 v3 = {a3.x * cid, a3.y * cid, a3.z * cid, a3.w * cid};
            __builtin_nontemporal_store(
                v3, reinterpret_cast<f32x4*>(out_id + (size_t)n * DD + l16 * 4));
            bf16x4 hb;
            hb[0] = (__bf16)(ax.x * cid); hb[1] = (__bf16)(ax.y * cid);
            hb[2] = (__bf16)(ax.z * cid); hb[3] = (__bf16)(ax.w * cid);
            *reinterpret_cast<bf16x4*>(&At[w][q * 4 + j][l16 * 4]) = hb;
            f32x4 s2v = {a2.x * cid, a2.y * cid, a2.z * cid, a2.w * cid};
            *reinterpret_cast<f32x4*>(&S2[w][q * 4 + j][l16 * 4]) = s2v;
            ax = make_float4(0.f, 0.f, 0.f, 0.f);
            a2 = make_float4(0.f, 0.f, 0.f, 0.f);
            a3 = make_float4(0.f, 0.f, 0.f, 0.f);
            ++j;
            bnd = (j < 4) ? offs[n0q + j + 1] : 0x7fffffff;
        }
        if (j == 4) break;

        const float cs = __int_as_float(ep.z);
        const float4 r = *reinterpret_cast<const float4*>(
            review + (size_t)ep.x * DD + l16 * 4);
        const bf16x8 t = *reinterpret_cast<const bf16x8*>(
            ftc + (size_t)ep.y * 128 + l16 * 8);
        ++pos;
        ep = epack[pos < posEnd ? pos : (NE - 1)];    // prefetch next slot

        ax.x = fmaf(r.x, cs, ax.x); ax.y = fmaf(r.y, cs, ax.y);
        ax.z = fmaf(r.z, cs, ax.z); ax.w = fmaf(r.w, cs, ax.w);
        a2.x += (float)t[0]; a2.y += (float)t[1];
        a2.z += (float)t[2]; a2.w += (float)t[3];
        a3.x += (float)t[4]; a3.y += (float)t[5];
        a3.z += (float)t[6]; a3.w += (float)t[7];
    }

    // Wave-synchronous LDS: drain ds_writes before the epilogue reads.
    asm volatile("s_waitcnt lgkmcnt(0)" ::: "memory");

    // Per-wave MFMA epilogue: out_re = A@W1^T, out_rst = S2 + A@W2^T.
    const bf16x8 a0 = *reinterpret_cast<const bf16x8*>(&At[w][l16][q * 8]);
    const bf16x8 a1 = *reinterpret_cast<const bf16x8*>(&At[w][l16][q * 8 + 32]);

    const f32x4 zero = {0.f, 0.f, 0.f, 0.f};
#pragma unroll
    for (int c = 0; c < 4; ++c) {
        const int off = (c * 16 + l16) * DD + q * 8;
        const bf16x8 w1f0 = pack8(W1 + off);
        const bf16x8 w1f1 = pack8(W1 + off + 32);
        const bf16x8 w2f0 = pack8(W2 + off);
        const bf16x8 w2f1 = pack8(W2 + off + 32);
        f32x4 acc1 = zero, acc2 = zero;
        acc1 = __builtin_amdgcn_mfma_f32_16x16x32_bf16(a0, w1f0, acc1, 0, 0, 0);
        acc1 = __builtin_amdgcn_mfma_f32_16x16x32_bf16(a1, w1f1, acc1, 0, 0, 0);
        acc2 = __builtin_amdgcn_mfma_f32_16x16x32_bf16(a0, w2f0, acc2, 0, 0, 0);
        acc2 = __builtin_amdgcn_mfma_f32_16x16x32_bf16(a1, w2f1, acc2, 0, 0, 0);
#pragma unroll
        for (int i = 0; i < 4; ++i) {
            const int row = q * 4 + i;
            const size_t o = (size_t)(wbase + row) * DD + c * 16 + l16;
            __builtin_nontemporal_store(acc1[i], out_re + o);
            __builtin_nontemporal_store(acc2[i] + S2[w][row][c * 16 + l16], out_rst + o);
        }
    }
}

// ---------- Fallback (round-2 proven kernel) if ws too small ----------
__global__ __launch_bounds__(256) void gcn_mfma_kernel(
    const int* __restrict__ src, const int* __restrict__ dst,
    const float* __restrict__ review, const float* __restrict__ ci,
    const float* __restrict__ W1, const float* __restrict__ W2,
    const float* __restrict__ f2, const float* __restrict__ f3,
    float* __restrict__ out)
{
    float* out_rst = out;
    float* out_re  = out + (size_t)NN * DD;
    float* out_id  = out + 2 * (size_t)NN * DD;
    const int lane = threadIdx.x & 63;
    const int l16  = lane & 15;
    const int lq   = lane >> 4;
    const int wid  = blockIdx.x * (blockDim.x >> 6) + (threadIdx.x >> 6);
    const int nw   = gridDim.x * (blockDim.x >> 6);

    bf16x8 w1f[4][2], w2f[4][2];
#pragma unroll
    for (int c = 0; c < 4; ++c)
#pragma unroll
        for (int kk = 0; kk < 2; ++kk) {
            const int off = (c * 16 + l16) * DD + kk * 32 + lq * 8;
            w1f[c][kk] = pack8(W1 + off);
            w2f[c][kk] = pack8(W2 + off);
        }
    const f32x4 zero = {0.f, 0.f, 0.f, 0.f};
    for (int t = wid; t < NE / 16; t += nw) {
        const int e0 = t * 16;
        const float* xr = review + (size_t)(e0 + l16) * DD + lq * 8;
        const bf16x8 a0 = pack8(xr);
        const bf16x8 a1 = pack8(xr + 32);
        f32x4 acc1[4], acc2[4];
#pragma unroll
        for (int c = 0; c < 4; ++c) { acc1[c] = zero; acc2[c] = zero; }
#pragma unroll
        for (int c = 0; c < 4; ++c) {
            acc1[c] = __builtin_amdgcn_mfma_f32_16x16x32_bf16(a0, w1f[c][0], acc1[c], 0, 0, 0);
            acc1[c] = __builtin_amdgcn_mfma_f32_16x16x32_bf16(a1, w1f[c][1], acc1[c], 0, 0, 0);
            acc2[c] = __builtin_amdgcn_mfma_f32_16x16x32_bf16(a0, w2f[c][0], acc2[c], 0, 0, 0);
            acc2[c] = __builtin_amdgcn_mfma_f32_16x16x32_bf16(a1, w2f[c][1], acc2[c], 0, 0, 0);
        }
        int sA[4], dA[4]; float cf[4];
#pragma unroll
        for (int i = 0; i < 4; ++i) {
            const int e = e0 + lq * 4 + i;
            sA[i] = src[e]; dA[i] = dst[e];
            cf[i] = ci[sA[i]] * ci[dA[i]];
        }
#pragma unroll
        for (int i = 0; i < 4; ++i) {
            const size_t so = (size_t)sA[i] * DD;
            const size_t dofs = (size_t)dA[i] * DD;
            const float c_ = cf[i];
#pragma unroll
            for (int c = 0; c < 4; ++c) {
                const int col = c * 16 + l16;
                atomicAdd(out_re  + dofs + col, acc1[c][i] * c_);
                atomicAdd(out_rst + dofs + col, (f2[so + col] + acc2[c][i]) * c_);
                atomicAdd(out_id  + dofs + col, f3[so + col] * c_);
            }
        }
    }
}

extern "C" void kernel_launch(void* const* d_in, const int* in_sizes, int n_in,
                              void* d_out, int out_size, void* d_ws, size_t ws_size,
                              hipStream_t stream) {
    const int*   src    = (const int*)d_in[0];
    const int*   dst    = (const int*)d_in[1];
    const float* review = (const float*)d_in[2];
    const float* ci     = (const float*)d_in[3];
    // d_in[4] = feature (unused by the reference computation)
    const float* W1     = (const float*)d_in[5];
    const float* W2     = (const float*)d_in[6];
    const float* f2     = (const float*)d_in[7];
    const float* f3     = (const float*)d_in[8];
    float* out = (float*)d_out;
    float* out_rst = out;
    float* out_re  = out + (size_t)NN * DD;
    float* out_id  = out + 2 * (size_t)NN * DD;

    // counts | offs(NN+1) | cursor | csum | cofs | epack(int4) | ftc(bf16 NN*128)
    const size_t NEED = sizeof(int) * ((size_t)3 * NN + 1 + 512) +
                        sizeof(int4) * (size_t)NE +
                        sizeof(__bf16) * (size_t)NN * 128;
    if (ws_size < NEED) {
        (void)hipMemsetAsync(out, 0, (size_t)out_size * sizeof(float), stream);
        gcn_mfma_kernel<<<2048, 256, 0, stream>>>(src, dst, review, ci, W1, W2, f2, f3, out);
        return;
    }

    char* w = (char*)d_ws;
    int* counts = (int*)w;    w += (size_t)NN * 4;
    int* offs   = (int*)w;    w += ((size_t)NN + 1) * 4;
    int* cursor = (int*)w;    w += (size_t)NN * 4;
    int* csum   = (int*)w;    w += 256 * 4;
    int* cofs   = (int*)w;    w += 256 * 4;
    int4* epack = (int4*)w;   w += (size_t)NE * 16;
    __bf16* ftc = (__bf16*)w;

    k_zero       <<<(NN / 4 + 255) / 256, 256, 0, stream>>>(counts);
    k_hist       <<<1024, 256, 0, stream>>>(dst, counts);
    k_chunk_sums <<<NCHUNK, 256, 0, stream>>>(counts, csum);
    k_scan_chunks<<<1, 64, 0, stream>>>(csum, cofs);
    k_chunk_scan <<<NCHUNK, 256, 0, stream>>>(counts, cofs, offs, cursor);
    k_fill_conv  <<<3072, 256, 0, stream>>>(dst, src, ci, f2, f3, cursor, epack, ftc);
    k_pull_ws    <<<NN / 64, 256, 0, stream>>>(epack, offs, review, ci, ftc,
                                               W1, W2, out_rst, out_re, out_id);
}